// Round 6
// baseline (10282.949 us; speedup 1.0000x reference)
//
#include <hip/hip_runtime.h>
#include <hip/hip_bf16.h>
#include <cstdint>
#include <cstddef>

// Model: B=1024, S=60, CIN=25, D=256, H=256, T=S+2=62
// Inputs fp32, output fp32; internal bf16 activations/weights, fp32 accum.
//
// Round-5 failure: 2x16-fragment ping-pong = 128 buffer VGPRs + 64 acc + bases
// > 256 v-reg architectural cap -> scratch spill (VGPR=256, FETCH 5.4 GB/dispatch,
// 2x slower). This round: pipeline at 8-fragment (gate-pair) granularity:
// A8[8]/B8[8] ping-pong = 64 buffer VGPRs, depth ~8-16 loads in flight/wave.
// Structural floor: per-CU L2 read BW (~60 B/cyc) x 1.5 MB weights/step.

typedef __attribute__((ext_vector_type(8))) short short8;
typedef __attribute__((ext_vector_type(4))) float floatx4;

#define BATCH 1024
#define TSTEPS 62

__device__ __forceinline__ float bf2f(short s) {
    union { unsigned u; float f; } v;
    v.u = ((unsigned)(unsigned short)s) << 16;
    return v.f;
}
__device__ __forceinline__ short f2bf(float f) {
    union { float f; unsigned u; } v; v.f = f;
    unsigned r = (v.u + 0x7fffu + ((v.u >> 16) & 1u)) >> 16;  // RNE
    return (short)r;
}
__device__ __forceinline__ float sigf(float x) { return 1.0f / (1.0f + __expf(-x)); }

// ------------- repack: Wcat[dir][row][k] = bf16([Wih row | Whh row]) -------
__global__ __launch_bounds__(256) void repack_kernel(
    const float* __restrict__ Wih, const float* __restrict__ Whh,
    short* __restrict__ Wcat, int XI)
{
    const int KK = XI + 256;
    int idx = blockIdx.x * 256 + threadIdx.x;
    if (idx >= 2 * 1024 * KK) return;
    int k   = idx % KK;
    int row = (idx / KK) & 1023;
    int dr  = idx / (1024 * KK);
    float v = (k < XI) ? Wih[((size_t)dr * 1024 + row) * XI + k]
                       : Whh[((size_t)dr * 1024 + row) * 256 + (k - XI)];
    Wcat[idx] = f2bf(v);
}

// ---------------- embed: seq[t][b][d] --------------------------------------
__global__ __launch_bounds__(256) void embed_kernel(
    const float* __restrict__ x, const float* __restrict__ Wg,
    const float* __restrict__ bg, const float* __restrict__ Wl,
    const float* __restrict__ bl, short* __restrict__ seq)
{
    const int b = blockIdx.x;
    const int d = threadIdx.x;  // 256 = D
    __shared__ float xs[1500];
    for (int i = d; i < 1500; i += 256) xs[i] = x[(size_t)b * 1500 + i];
    __syncthreads();

    float g = bg[d];
#pragma unroll
    for (int c = 0; c < 16; ++c) g += xs[9 + c] * Wg[d * 16 + c];
    short gb = f2bf(g);
    seq[((size_t)0 * BATCH + b) * 256 + d] = gb;
    seq[((size_t)61 * BATCH + b) * 256 + d] = gb;

    for (int t = 0; t < 60; ++t) {
        float v = bl[d];
#pragma unroll
        for (int c = 0; c < 9; ++c) v += xs[t * 25 + c] * Wl[d * 9 + c];
        seq[((size_t)(t + 1) * BATCH + b) * 256 + d] = f2bf(v);
    }
}

// ---------------- persistent biLSTM layer ----------------------------------
// fragment f in group (kb,gh): g = 2*gh + (f>>2), s = f&3
// row offset from wb = (g*256 + s*16)*KK, k offset = kb*32
#define GOFF(gh, f, kb) \
    ((size_t)(((2 * (gh) + ((f) >> 2)) * 256 + ((f) & 3) * 16)) * KK + (size_t)(kb) * 32)
#define LOADG(BUF, gh, kb)                                                       \
    {                                                                            \
        _Pragma("unroll")                                                        \
        for (int f = 0; f < 8; ++f)                                              \
            BUF[f] = *reinterpret_cast<const short8*>(wb + GOFF(gh, f, kb));     \
    }
#define LOADA(DST, kb)                                                           \
    {                                                                            \
        DST = ((kb) < XB)                                                        \
            ? *reinterpret_cast<const short8*>(Xrow + (kb) * 32)                 \
            : *reinterpret_cast<const short8*>(&h_lds[lr][((kb) - XB) * 32 + quad * 8]); \
    }
#define MFMA8(AV, BUF, gh)                                                       \
    {                                                                            \
        _Pragma("unroll")                                                        \
        for (int f = 0; f < 8; ++f)                                              \
            acc[(2 * (gh) + (f >> 2)) * 4 + (f & 3)] =                           \
                __builtin_amdgcn_mfma_f32_16x16x32_bf16(AV, BUF[f],              \
                    acc[(2 * (gh) + (f >> 2)) * 4 + (f & 3)], 0, 0, 0);          \
    }

template <int KK>  // 512 (layer0: XI=256) or 768 (layer1: XI=512)
__global__ __launch_bounds__(256, 1) void lstm_kernel(
    const short* __restrict__ X,      // (62,1024,XI) bf16 time-major
    const short* __restrict__ Wcat,   // (2,1024,KK) bf16  [Wih|Whh]
    const float* __restrict__ bih,    // (2,1024) fp32
    const float* __restrict__ bhh,    // (2,1024) fp32
    short* __restrict__ Hout)         // (62,1024,512); dir d -> cols [256d,..)
{
    constexpr int XI = KK - 256;
    constexpr int KB = KK / 32;   // 16 or 24 (even)
    constexpr int XB = XI / 32;

    const int wg    = blockIdx.x;     // 128 = 64 tiles x 2 dirs
    const int dir   = wg >> 6;
    const int bbase = (wg & 63) * 16;
    const int tid   = threadIdx.x;
    const int wv    = tid >> 6;       // wave -> hidden units [64wv,64wv+64)
    const int lane  = tid & 63;
    const int quad  = lane >> 4;      // C rows quad*4..+3 ; A/B k-offset quad*8
    const int lr    = lane & 15;      // A row (batch) / B row (gate col) / C col

    __shared__ __align__(16) short h_lds[16][264];  // +8 pad
    for (int i = tid; i < 16 * 264; i += 256) (&h_lds[0][0])[i] = 0;

    // per-lane weight base: row component (wv*64 + lr), k component quad*8
    const short* wb = Wcat + (size_t)dir * 1024 * KK +
                      (size_t)(wv * 64 + lr) * KK + quad * 8;

    float bias_v[16];
#pragma unroll
    for (int g = 0; g < 4; ++g)
#pragma unroll
        for (int s = 0; s < 4; ++s) {
            int col = g * 256 + wv * 64 + s * 16 + lr;
            bias_v[g * 4 + s] = bih[dir * 1024 + col] + bhh[dir * 1024 + col];
        }
    float c_st[4][4];
#pragma unroll
    for (int s = 0; s < 4; ++s)
#pragma unroll
        for (int r = 0; r < 4; ++r) c_st[s][r] = 0.0f;

    __syncthreads();

    for (int st = 0; st < TSTEPS; ++st) {
        const int t = dir ? (TSTEPS - 1 - st) : st;
        const short* Xrow = X + ((size_t)t * BATCH + bbase + lr) * XI + quad * 8;

        floatx4 acc[16];
#pragma unroll
        for (int i = 0; i < 16; ++i) {
            float bv = bias_v[i];
            acc[i] = (floatx4){bv, bv, bv, bv};
        }

        // software pipeline, 8-fragment (gate-pair) granularity, ping-pong A8/B8
        short8 A8[8], B8[8], a_cur, a_nxt;
        LOADG(A8, 0, 0);
        LOADA(a_cur, 0);
#pragma unroll
        for (int kb = 0; kb < KB; ++kb) {
            LOADG(B8, 1, kb);               // prefetch group (kb, gh=1)
            if (kb + 1 < KB) LOADA(a_nxt, kb + 1);
            MFMA8(a_cur, A8, 0);            // consume group (kb, gh=0)
            if (kb + 1 < KB) LOADG(A8, 0, kb + 1);  // prefetch (kb+1, gh=0)
            MFMA8(a_cur, B8, 1);            // consume group (kb, gh=1)
            a_cur = a_nxt;
        }

        __syncthreads();  // all waves done reading h_lds

        // cell update, in-register (i,f,g,o co-located per lane)
#pragma unroll
        for (int s = 0; s < 4; ++s) {
#pragma unroll
            for (int r = 0; r < 4; ++r) {
                float iv = acc[0 * 4 + s][r], fv = acc[1 * 4 + s][r];
                float gv = acc[2 * 4 + s][r], ov = acc[3 * 4 + s][r];
                float c = sigf(fv) * c_st[s][r] + sigf(iv) * tanhf(gv);
                c_st[s][r] = c;
                float h = sigf(ov) * tanhf(c);
                short hb = f2bf(h);
                int m = quad * 4 + r;
                int j = wv * 64 + s * 16 + lr;
                h_lds[m][j] = hb;
                Hout[((size_t)t * BATCH + bbase + m) * 512 + dir * 256 + j] = hb;
            }
        }
        __syncthreads();  // new h visible before next step
    }
}

// ---------------- heads (fp32 output) --------------------------------------
__global__ __launch_bounds__(256) void lout_kernel(
    const short* __restrict__ h1, const float* __restrict__ Wlp,
    const float* __restrict__ blp, float* __restrict__ out)
{
    __shared__ float wl[6 * 512];
    for (int i = threadIdx.x; i < 6 * 512; i += 256) wl[i] = Wlp[i];
    __syncthreads();

    int idx = blockIdx.x * 256 + threadIdx.x;
    if (idx >= BATCH * 60) return;
    int b = idx & (BATCH - 1);
    int s = idx >> 10;
    const short* hrow = h1 + ((size_t)(s + 1) * BATCH + b) * 512;

    float acc[6];
#pragma unroll
    for (int j = 0; j < 6; ++j) acc[j] = blp[j];
    for (int k = 0; k < 512; k += 8) {
        short8 hv = *reinterpret_cast<const short8*>(hrow + k);
#pragma unroll
        for (int e = 0; e < 8; ++e) {
            float h = bf2f(hv[e]);
#pragma unroll
            for (int j = 0; j < 6; ++j) acc[j] += h * wl[j * 512 + k + e];
        }
    }
    float* orow = out + ((size_t)b * 60 + s) * 14;
#pragma unroll
    for (int j = 0; j < 6; ++j) orow[j] = acc[j];
}

__global__ __launch_bounds__(256) void gout_kernel(
    const short* __restrict__ h1, const float* __restrict__ Wgp,
    const float* __restrict__ bgp, float* __restrict__ out)
{
    __shared__ float wg[8 * 1024];
    for (int i = threadIdx.x; i < 8 * 1024; i += 256) wg[i] = Wgp[i];
    __syncthreads();

    int b = blockIdx.x * 256 + threadIdx.x;
    if (b >= BATCH) return;
    const short* ha = h1 + (size_t)b * 512;
    const short* hb = h1 + ((size_t)61 * BATCH + b) * 512;

    float acc[8];
#pragma unroll
    for (int j = 0; j < 8; ++j) acc[j] = bgp[j];
    for (int k = 0; k < 512; k += 8) {
        short8 h1v = *reinterpret_cast<const short8*>(ha + k);
        short8 h2v = *reinterpret_cast<const short8*>(hb + k);
#pragma unroll
        for (int e = 0; e < 8; ++e) {
            float v1 = bf2f(h1v[e]);
            float v2 = bf2f(h2v[e]);
#pragma unroll
            for (int j = 0; j < 8; ++j) {
                acc[j] += v1 * wg[j * 1024 + k + e];
                acc[j] += v2 * wg[j * 1024 + 512 + k + e];
            }
        }
    }
    for (int s = 0; s < 60; ++s) {
        float* orow = out + ((size_t)b * 60 + s) * 14 + 6;
#pragma unroll
        for (int j = 0; j < 8; ++j) orow[j] = acc[j];
    }
}

// ---------------- launch ---------------------------------------------------
extern "C" void kernel_launch(void* const* d_in, const int* in_sizes, int n_in,
                              void* d_out, int out_size, void* d_ws, size_t ws_size,
                              hipStream_t stream)
{
    const float* x    = (const float*)d_in[0];
    const float* Wg   = (const float*)d_in[1];
    const float* bg   = (const float*)d_in[2];
    const float* Wl   = (const float*)d_in[3];
    const float* bl   = (const float*)d_in[4];
    const float* Wih0 = (const float*)d_in[5];
    const float* Whh0 = (const float*)d_in[6];
    const float* bih0 = (const float*)d_in[7];
    const float* bhh0 = (const float*)d_in[8];
    const float* Wih1 = (const float*)d_in[9];
    const float* Whh1 = (const float*)d_in[10];
    const float* bih1 = (const float*)d_in[11];
    const float* bhh1 = (const float*)d_in[12];
    const float* Wgp  = (const float*)d_in[13];
    const float* bgp  = (const float*)d_in[14];
    const float* Wlp  = (const float*)d_in[15];
    const float* blp  = (const float*)d_in[16];
    float* out = (float*)d_out;

    const size_t seq_elems = (size_t)TSTEPS * BATCH * 256;   // 16,252,928
    const size_t h_elems   = (size_t)TSTEPS * BATCH * 512;   // 32,505,856
    const int    w0_elems  = 2 * 1024 * 512;                 // 1,048,576
    const int    w1_elems  = 2 * 1024 * 768;                 // 1,572,864

    short* seq   = (short*)d_ws;
    short* h0    = seq + seq_elems;
    short* h1    = h0 + h_elems;
    short* wcat0 = h1 + h_elems;
    short* wcat1 = wcat0 + w0_elems;
    const size_t need = (seq_elems + 2 * h_elems + w0_elems + w1_elems) * sizeof(short);
    if (ws_size < need) return;

    repack_kernel<<<(w0_elems + 255) / 256, 256, 0, stream>>>(Wih0, Whh0, wcat0, 256);
    repack_kernel<<<(w1_elems + 255) / 256, 256, 0, stream>>>(Wih1, Whh1, wcat1, 512);

    embed_kernel<<<BATCH, 256, 0, stream>>>(x, Wg, bg, Wl, bl, seq);
    lstm_kernel<512><<<128, 256, 0, stream>>>(seq, wcat0, bih0, bhh0, h0);
    lstm_kernel<768><<<128, 256, 0, stream>>>(h0, wcat1, bih1, bhh1, h1);
    lout_kernel<<<(BATCH * 60 + 255) / 256, 256, 0, stream>>>(h1, Wlp, blp, out);
    gout_kernel<<<(BATCH + 255) / 256, 256, 0, stream>>>(h1, Wgp, bgp, out);
}

// Round 7
// 2032.800 us; speedup vs baseline: 5.0585x; 5.0585x over previous
//
#include <hip/hip_runtime.h>
#include <hip/hip_bf16.h>
#include <cstdint>
#include <cstddef>

// Model: B=1024, S=60, CIN=25, D=256, H=256, T=S+2=62
// Inputs fp32, output fp32; internal bf16 activations/weights, fp32 accum.
//
// Round-5/6 failure: fully-unrolled K-loop (KB compile-time) let the scheduler
// hoist loads across iterations -> >256 live VGPRs -> scratch spill (VGPR=256,
// FETCH 5 GB = spill + L2 thrash of the weight stream). Fix:
//   (1) #pragma unroll 1 dynamic kb loop, 8-fragment lookahead ping-pong,
//       peeled last iteration -> live set ~210 VGPRs, hoisting bounded.
//   (2) wave-local weight repack Wp[dir][wv][kb][frag16][lane][8]: per-kb the
//       wave reads one contiguous 16 KB block; per-lane address = base+lane*16B,
//       fragment stride 1 KB; one pointer increment (16 KB) per iteration.

typedef __attribute__((ext_vector_type(8))) short short8;
typedef __attribute__((ext_vector_type(4))) float floatx4;

#define BATCH 1024
#define TSTEPS 62

__device__ __forceinline__ float bf2f(short s) {
    union { unsigned u; float f; } v;
    v.u = ((unsigned)(unsigned short)s) << 16;
    return v.f;
}
__device__ __forceinline__ short f2bf(float f) {
    union { float f; unsigned u; } v; v.f = f;
    unsigned r = (v.u + 0x7fffu + ((v.u >> 16) & 1u)) >> 16;  // RNE
    return (short)r;
}
__device__ __forceinline__ float sigf(float x) { return 1.0f / (1.0f + __expf(-x)); }

// ------------- repack into wave-local blocked layout -----------------------
// dst idx = ((((dr*4 + wv)*KB + kb)*16 + gs)*64 + lane)*8 + j
// maps to src row = (gs>>2)*256 + wv*64 + (gs&3)*16 + (lane&15),
//          src k  = kb*32 + (lane>>4)*8 + j   (k<XI: Wih, else Whh[k-XI])
__global__ __launch_bounds__(256) void repack_kernel(
    const float* __restrict__ Wih, const float* __restrict__ Whh,
    short* __restrict__ Wp, int XI)
{
    const int KB = (XI + 256) / 32;
    int idx = blockIdx.x * 256 + threadIdx.x;
    if (idx >= 8 * KB * 8192) return;  // 2 dirs * 4 waves * KB * 16*64*8
    int j    = idx & 7;
    int lane = (idx >> 3) & 63;
    int gs   = (idx >> 9) & 15;
    int rem  = idx >> 13;
    int kb   = rem % KB;
    int rem2 = rem / KB;
    int wv   = rem2 & 3;
    int dr   = rem2 >> 2;
    int row  = (gs >> 2) * 256 + wv * 64 + (gs & 3) * 16 + (lane & 15);
    int k    = kb * 32 + (lane >> 4) * 8 + j;
    float v = (k < XI) ? Wih[((size_t)dr * 1024 + row) * XI + k]
                       : Whh[((size_t)dr * 1024 + row) * 256 + (k - XI)];
    Wp[idx] = f2bf(v);
}

// ---------------- embed: seq[t][b][d] --------------------------------------
__global__ __launch_bounds__(256) void embed_kernel(
    const float* __restrict__ x, const float* __restrict__ Wg,
    const float* __restrict__ bg, const float* __restrict__ Wl,
    const float* __restrict__ bl, short* __restrict__ seq)
{
    const int b = blockIdx.x;
    const int d = threadIdx.x;  // 256 = D
    __shared__ float xs[1500];
    for (int i = d; i < 1500; i += 256) xs[i] = x[(size_t)b * 1500 + i];
    __syncthreads();

    float g = bg[d];
#pragma unroll
    for (int c = 0; c < 16; ++c) g += xs[9 + c] * Wg[d * 16 + c];
    short gb = f2bf(g);
    seq[((size_t)0 * BATCH + b) * 256 + d] = gb;
    seq[((size_t)61 * BATCH + b) * 256 + d] = gb;

    for (int t = 0; t < 60; ++t) {
        float v = bl[d];
#pragma unroll
        for (int c = 0; c < 9; ++c) v += xs[t * 25 + c] * Wl[d * 9 + c];
        seq[((size_t)(t + 1) * BATCH + b) * 256 + d] = f2bf(v);
    }
}

// ---------------- persistent biLSTM layer ----------------------------------
#define LOADG8(BUF, P, gh)                                                       \
    {                                                                            \
        _Pragma("unroll")                                                        \
        for (int f = 0; f < 8; ++f)                                              \
            BUF[f] = *reinterpret_cast<const short8*>((P) + ((gh) * 8 + f) * 512); \
    }
#define MFMA8(AV, BUF, gh)                                                       \
    {                                                                            \
        _Pragma("unroll")                                                        \
        for (int f = 0; f < 8; ++f)                                              \
            acc[(gh) * 8 + f] = __builtin_amdgcn_mfma_f32_16x16x32_bf16(         \
                AV, BUF[f], acc[(gh) * 8 + f], 0, 0, 0);                         \
    }

template <int KK>  // 512 (layer0: XI=256) or 768 (layer1: XI=512)
__global__ __launch_bounds__(256, 1) void lstm_kernel(
    const short* __restrict__ X,      // (62,1024,XI) bf16 time-major
    const short* __restrict__ Wp,     // blocked weights, see repack_kernel
    const float* __restrict__ bih,    // (2,1024) fp32
    const float* __restrict__ bhh,    // (2,1024) fp32
    short* __restrict__ Hout)         // (62,1024,512); dir d -> cols [256d,..)
{
    constexpr int XI = KK - 256;
    constexpr int KB = KK / 32;   // 16 or 24
    constexpr int XB = XI / 32;

    const int wg    = blockIdx.x;     // 128 = 64 tiles x 2 dirs
    const int dir   = wg >> 6;
    const int bbase = (wg & 63) * 16;
    const int tid   = threadIdx.x;
    const int wv    = tid >> 6;       // wave -> hidden units [64wv,64wv+64)
    const int lane  = tid & 63;
    const int quad  = lane >> 4;      // C rows quad*4..+3 ; A k-offset quad*8
    const int lr    = lane & 15;      // A row (batch) / C col

    __shared__ __align__(16) short h_lds[16][264];  // +8 pad
    for (int i = tid; i < 16 * 264; i += 256) (&h_lds[0][0])[i] = 0;

    // wave-local weight base (fragment i at +i*512, kb block at +kb*8192)
    const short* wpb = Wp + (((size_t)(dir * 4 + wv) * KB) << 13) + lane * 8;

    float bias_v[16];
#pragma unroll
    for (int g = 0; g < 4; ++g)
#pragma unroll
        for (int s = 0; s < 4; ++s) {
            int col = g * 256 + wv * 64 + s * 16 + lr;
            bias_v[g * 4 + s] = bih[dir * 1024 + col] + bhh[dir * 1024 + col];
        }
    float c_st[4][4];
#pragma unroll
    for (int s = 0; s < 4; ++s)
#pragma unroll
        for (int r = 0; r < 4; ++r) c_st[s][r] = 0.0f;

    __syncthreads();

    for (int st = 0; st < TSTEPS; ++st) {
        const int t = dir ? (TSTEPS - 1 - st) : st;
        const short* Xrow = X + ((size_t)t * BATCH + bbase + lr) * XI + quad * 8;

        floatx4 acc[16];
#pragma unroll
        for (int i = 0; i < 16; ++i) {
            float bv = bias_v[i];
            acc[i] = (floatx4){bv, bv, bv, bv};
        }

        // software pipeline: 8-frag lookahead, dynamic loop (no full unroll)
        short8 A8[8], B8[8], a_cur, a_nxt;
        const short* blk = wpb;
        LOADG8(A8, blk, 0);
        a_cur = *reinterpret_cast<const short8*>(Xrow);  // kb=0 < XB always
#pragma unroll 1
        for (int kb = 0; kb < KB - 1; ++kb) {
            LOADG8(B8, blk, 1);
            if (kb + 1 < XB)
                a_nxt = *reinterpret_cast<const short8*>(Xrow + (kb + 1) * 32);
            else
                a_nxt = *reinterpret_cast<const short8*>(
                    &h_lds[lr][(kb + 1 - XB) * 32 + quad * 8]);
            MFMA8(a_cur, A8, 0);
            LOADG8(A8, blk + 8192, 0);   // next kb, group 0
            MFMA8(a_cur, B8, 1);
            a_cur = a_nxt;
            blk += 8192;
        }
        // epilogue: kb = KB-1
        LOADG8(B8, blk, 1);
        MFMA8(a_cur, A8, 0);
        MFMA8(a_cur, B8, 1);

        __syncthreads();  // all waves done reading h_lds

        // cell update, in-register (i,f,g,o co-located per lane)
#pragma unroll
        for (int s = 0; s < 4; ++s) {
#pragma unroll
            for (int r = 0; r < 4; ++r) {
                float iv = acc[0 * 4 + s][r], fv = acc[1 * 4 + s][r];
                float gv = acc[2 * 4 + s][r], ov = acc[3 * 4 + s][r];
                float c = sigf(fv) * c_st[s][r] + sigf(iv) * tanhf(gv);
                c_st[s][r] = c;
                float h = sigf(ov) * tanhf(c);
                short hb = f2bf(h);
                int m = quad * 4 + r;
                int j = wv * 64 + s * 16 + lr;
                h_lds[m][j] = hb;
                Hout[((size_t)t * BATCH + bbase + m) * 512 + dir * 256 + j] = hb;
            }
        }
        __syncthreads();  // new h visible before next step
    }
}

// ---------------- heads (fp32 output) --------------------------------------
__global__ __launch_bounds__(256) void lout_kernel(
    const short* __restrict__ h1, const float* __restrict__ Wlp,
    const float* __restrict__ blp, float* __restrict__ out)
{
    __shared__ float wl[6 * 512];
    for (int i = threadIdx.x; i < 6 * 512; i += 256) wl[i] = Wlp[i];
    __syncthreads();

    int idx = blockIdx.x * 256 + threadIdx.x;
    if (idx >= BATCH * 60) return;
    int b = idx & (BATCH - 1);
    int s = idx >> 10;
    const short* hrow = h1 + ((size_t)(s + 1) * BATCH + b) * 512;

    float acc[6];
#pragma unroll
    for (int j = 0; j < 6; ++j) acc[j] = blp[j];
    for (int k = 0; k < 512; k += 8) {
        short8 hv = *reinterpret_cast<const short8*>(hrow + k);
#pragma unroll
        for (int e = 0; e < 8; ++e) {
            float h = bf2f(hv[e]);
#pragma unroll
            for (int j = 0; j < 6; ++j) acc[j] += h * wl[j * 512 + k + e];
        }
    }
    float* orow = out + ((size_t)b * 60 + s) * 14;
#pragma unroll
    for (int j = 0; j < 6; ++j) orow[j] = acc[j];
}

__global__ __launch_bounds__(256) void gout_kernel(
    const short* __restrict__ h1, const float* __restrict__ Wgp,
    const float* __restrict__ bgp, float* __restrict__ out)
{
    __shared__ float wg[8 * 1024];
    for (int i = threadIdx.x; i < 8 * 1024; i += 256) wg[i] = Wgp[i];
    __syncthreads();

    int b = blockIdx.x * 256 + threadIdx.x;
    if (b >= BATCH) return;
    const short* ha = h1 + (size_t)b * 512;
    const short* hb = h1 + ((size_t)61 * BATCH + b) * 512;

    float acc[8];
#pragma unroll
    for (int j = 0; j < 8; ++j) acc[j] = bgp[j];
    for (int k = 0; k < 512; k += 8) {
        short8 h1v = *reinterpret_cast<const short8*>(ha + k);
        short8 h2v = *reinterpret_cast<const short8*>(hb + k);
#pragma unroll
        for (int e = 0; e < 8; ++e) {
            float v1 = bf2f(h1v[e]);
            float v2 = bf2f(h2v[e]);
#pragma unroll
            for (int j = 0; j < 8; ++j) {
                acc[j] += v1 * wg[j * 1024 + k + e];
                acc[j] += v2 * wg[j * 1024 + 512 + k + e];
            }
        }
    }
    for (int s = 0; s < 60; ++s) {
        float* orow = out + ((size_t)b * 60 + s) * 14 + 6;
#pragma unroll
        for (int j = 0; j < 8; ++j) orow[j] = acc[j];
    }
}

// ---------------- launch ---------------------------------------------------
extern "C" void kernel_launch(void* const* d_in, const int* in_sizes, int n_in,
                              void* d_out, int out_size, void* d_ws, size_t ws_size,
                              hipStream_t stream)
{
    const float* x    = (const float*)d_in[0];
    const float* Wg   = (const float*)d_in[1];
    const float* bg   = (const float*)d_in[2];
    const float* Wl   = (const float*)d_in[3];
    const float* bl   = (const float*)d_in[4];
    const float* Wih0 = (const float*)d_in[5];
    const float* Whh0 = (const float*)d_in[6];
    const float* bih0 = (const float*)d_in[7];
    const float* bhh0 = (const float*)d_in[8];
    const float* Wih1 = (const float*)d_in[9];
    const float* Whh1 = (const float*)d_in[10];
    const float* bih1 = (const float*)d_in[11];
    const float* bhh1 = (const float*)d_in[12];
    const float* Wgp  = (const float*)d_in[13];
    const float* bgp  = (const float*)d_in[14];
    const float* Wlp  = (const float*)d_in[15];
    const float* blp  = (const float*)d_in[16];
    float* out = (float*)d_out;

    const size_t seq_elems = (size_t)TSTEPS * BATCH * 256;   // 16,252,928
    const size_t h_elems   = (size_t)TSTEPS * BATCH * 512;   // 32,505,856
    const int    w0_elems  = 2 * 1024 * 512;                 // 1,048,576 (=8*16*8192)
    const int    w1_elems  = 2 * 1024 * 768;                 // 1,572,864 (=8*24*8192)

    short* seq = (short*)d_ws;
    short* h0  = seq + seq_elems;
    short* h1  = h0 + h_elems;
    short* wp0 = h1 + h_elems;
    short* wp1 = wp0 + w0_elems;
    const size_t need = (seq_elems + 2 * h_elems + w0_elems + w1_elems) * sizeof(short);
    if (ws_size < need) return;

    repack_kernel<<<(w0_elems + 255) / 256, 256, 0, stream>>>(Wih0, Whh0, wp0, 256);
    repack_kernel<<<(w1_elems + 255) / 256, 256, 0, stream>>>(Wih1, Whh1, wp1, 512);

    embed_kernel<<<BATCH, 256, 0, stream>>>(x, Wg, bg, Wl, bl, seq);
    lstm_kernel<512><<<128, 256, 0, stream>>>(seq, wp0, bih0, bhh0, h0);
    lstm_kernel<768><<<128, 256, 0, stream>>>(h0, wp1, bih1, bhh1, h1);
    lout_kernel<<<(BATCH * 60 + 255) / 256, 256, 0, stream>>>(h1, Wlp, blp, out);
    gout_kernel<<<(BATCH + 255) / 256, 256, 0, stream>>>(h1, Wgp, bgp, out);
}

// Round 8
// 1812.830 us; speedup vs baseline: 5.6723x; 1.1213x over previous
//
#include <hip/hip_runtime.h>
#include <hip/hip_bf16.h>
#include <cstdint>
#include <cstddef>

// Model: B=1024, S=60, CIN=25, D=256, H=256, T=S+2=62
// Inputs fp32, output fp32; internal bf16 activations/weights, fp32 accum.
//
// Round-7 analysis: distance-1 prefetch leaves ~350 cyc/kb of exposed L2
// latency (per-CU pull 86 GB/s << 135-154 GB/s port ceiling) + libm tanh in
// the cell update. Round 8:
//   (1) distance-2 prefetch: X0,X1,Y0,Y1 named buffers, 2-kb unroll-1 loop —
//       each 8-load group covered by ~256 cyc of MFMA before consumption.
//   (2) bias -> LDS (frees 16 VGPRs), acc zero-init. Live set ~230 VGPRs.
//   (3) sigmoid/tanh via v_exp_f32 + v_rcp_f32 (no libm, no fdiv).

typedef __attribute__((ext_vector_type(8))) short short8;
typedef __attribute__((ext_vector_type(4))) float floatx4;

#define BATCH 1024
#define TSTEPS 62

__device__ __forceinline__ float bf2f(short s) {
    union { unsigned u; float f; } v;
    v.u = ((unsigned)(unsigned short)s) << 16;
    return v.f;
}
__device__ __forceinline__ short f2bf(float f) {
    union { float f; unsigned u; } v; v.f = f;
    unsigned r = (v.u + 0x7fffu + ((v.u >> 16) & 1u)) >> 16;  // RNE
    return (short)r;
}
// fast gates: v_exp_f32 + v_rcp_f32; rel err ~1e-6 << bf16 h rounding (4e-3)
__device__ __forceinline__ float sigf(float x) {
    return __builtin_amdgcn_rcpf(1.0f + __expf(-x));
}
__device__ __forceinline__ float tanhf_fast(float x) {
    return 2.0f * __builtin_amdgcn_rcpf(1.0f + __expf(-2.0f * x)) - 1.0f;
}

// ------------- repack into wave-local blocked layout -----------------------
// dst idx = ((((dr*4 + wv)*KB + kb)*16 + gs)*64 + lane)*8 + j
// maps to src row = (gs>>2)*256 + wv*64 + (gs&3)*16 + (lane&15),
//          src k  = kb*32 + (lane>>4)*8 + j   (k<XI: Wih, else Whh[k-XI])
__global__ __launch_bounds__(256) void repack_kernel(
    const float* __restrict__ Wih, const float* __restrict__ Whh,
    short* __restrict__ Wp, int XI)
{
    const int KB = (XI + 256) / 32;
    int idx = blockIdx.x * 256 + threadIdx.x;
    if (idx >= 8 * KB * 8192) return;  // 2 dirs * 4 waves * KB * 16*64*8
    int j    = idx & 7;
    int lane = (idx >> 3) & 63;
    int gs   = (idx >> 9) & 15;
    int rem  = idx >> 13;
    int kb   = rem % KB;
    int rem2 = rem / KB;
    int wv   = rem2 & 3;
    int dr   = rem2 >> 2;
    int row  = (gs >> 2) * 256 + wv * 64 + (gs & 3) * 16 + (lane & 15);
    int k    = kb * 32 + (lane >> 4) * 8 + j;
    float v = (k < XI) ? Wih[((size_t)dr * 1024 + row) * XI + k]
                       : Whh[((size_t)dr * 1024 + row) * 256 + (k - XI)];
    Wp[idx] = f2bf(v);
}

// ---------------- embed: seq[t][b][d] --------------------------------------
__global__ __launch_bounds__(256) void embed_kernel(
    const float* __restrict__ x, const float* __restrict__ Wg,
    const float* __restrict__ bg, const float* __restrict__ Wl,
    const float* __restrict__ bl, short* __restrict__ seq)
{
    const int b = blockIdx.x;
    const int d = threadIdx.x;  // 256 = D
    __shared__ float xs[1500];
    for (int i = d; i < 1500; i += 256) xs[i] = x[(size_t)b * 1500 + i];
    __syncthreads();

    float g = bg[d];
#pragma unroll
    for (int c = 0; c < 16; ++c) g += xs[9 + c] * Wg[d * 16 + c];
    short gb = f2bf(g);
    seq[((size_t)0 * BATCH + b) * 256 + d] = gb;
    seq[((size_t)61 * BATCH + b) * 256 + d] = gb;

    for (int t = 0; t < 60; ++t) {
        float v = bl[d];
#pragma unroll
        for (int c = 0; c < 9; ++c) v += xs[t * 25 + c] * Wl[d * 9 + c];
        seq[((size_t)(t + 1) * BATCH + b) * 256 + d] = f2bf(v);
    }
}

// ---------------- persistent biLSTM layer ----------------------------------
#define LOADG8(BUF, P, gh)                                                       \
    {                                                                            \
        _Pragma("unroll")                                                        \
        for (int f = 0; f < 8; ++f)                                              \
            BUF[f] = *reinterpret_cast<const short8*>((P) + ((gh) * 8 + f) * 512); \
    }
#define LOADA(DST, kb)                                                           \
    {                                                                            \
        DST = ((kb) < XB)                                                        \
            ? *reinterpret_cast<const short8*>(Xrow + (kb) * 32)                 \
            : *reinterpret_cast<const short8*>(&h_lds[lr][((kb) - XB) * 32 + quad * 8]); \
    }
#define MFMA8(AV, BUF, gh)                                                       \
    {                                                                            \
        _Pragma("unroll")                                                        \
        for (int f = 0; f < 8; ++f)                                              \
            acc[(gh) * 8 + f] = __builtin_amdgcn_mfma_f32_16x16x32_bf16(         \
                AV, BUF[f], acc[(gh) * 8 + f], 0, 0, 0);                         \
    }

template <int KK>  // 512 (layer0: XI=256) or 768 (layer1: XI=512)
__global__ __launch_bounds__(256, 1) void lstm_kernel(
    const short* __restrict__ X,      // (62,1024,XI) bf16 time-major
    const short* __restrict__ Wp,     // blocked weights, see repack_kernel
    const float* __restrict__ bih,    // (2,1024) fp32
    const float* __restrict__ bhh,    // (2,1024) fp32
    short* __restrict__ Hout)         // (62,1024,512); dir d -> cols [256d,..)
{
    constexpr int XI = KK - 256;
    constexpr int KB = KK / 32;   // 16 or 24 (even)
    constexpr int XB = XI / 32;

    const int wg    = blockIdx.x;     // 128 = 64 tiles x 2 dirs
    const int dir   = wg >> 6;
    const int bbase = (wg & 63) * 16;
    const int tid   = threadIdx.x;
    const int wv    = tid >> 6;       // wave -> hidden units [64wv,64wv+64)
    const int lane  = tid & 63;
    const int quad  = lane >> 4;      // C rows quad*4..+3 ; A k-offset quad*8
    const int lr    = lane & 15;      // A row (batch) / C col

    __shared__ __align__(16) short h_lds[16][264];  // +8 pad
    __shared__ float bias_sh[1024];
    for (int i = tid; i < 16 * 264; i += 256) (&h_lds[0][0])[i] = 0;
    for (int i = tid; i < 1024; i += 256)
        bias_sh[i] = bih[dir * 1024 + i] + bhh[dir * 1024 + i];

    // wave-local weight base (fragment i at +i*512, kb block at +kb*8192)
    const short* wpb = Wp + (((size_t)(dir * 4 + wv) * KB) << 13) + lane * 8;

    float c_st[4][4];
#pragma unroll
    for (int s = 0; s < 4; ++s)
#pragma unroll
        for (int r = 0; r < 4; ++r) c_st[s][r] = 0.0f;

    __syncthreads();

    for (int st = 0; st < TSTEPS; ++st) {
        const int t = dir ? (TSTEPS - 1 - st) : st;
        const short* Xrow = X + ((size_t)t * BATCH + bbase + lr) * XI + quad * 8;

        floatx4 acc[16];
#pragma unroll
        for (int i = 0; i < 16; ++i) acc[i] = (floatx4){0.f, 0.f, 0.f, 0.f};

        // distance-2 software pipeline: X pair = kb, Y pair = kb+1 in flight
        short8 X0[8], X1[8], Y0[8], Y1[8], a_cur, a_nxt;
        const short* blk = wpb;
        LOADG8(X0, blk, 0);
        LOADG8(X1, blk, 1);
        a_cur = *reinterpret_cast<const short8*>(Xrow);  // kb=0 < XB always
#pragma unroll 1
        for (int kb = 0; kb < KB - 2; kb += 2) {
            // phase A: prefetch kb+1 (Y), consume kb (X)
            LOADG8(Y0, blk + 8192, 0);
            LOADG8(Y1, blk + 8192, 1);
            LOADA(a_nxt, kb + 1);
            MFMA8(a_cur, X0, 0);
            MFMA8(a_cur, X1, 1);
            a_cur = a_nxt;
            // phase B: prefetch kb+2 (X), consume kb+1 (Y)
            LOADG8(X0, blk + 2 * 8192, 0);
            LOADG8(X1, blk + 2 * 8192, 1);
            LOADA(a_nxt, kb + 2);
            MFMA8(a_cur, Y0, 0);
            MFMA8(a_cur, Y1, 1);
            a_cur = a_nxt;
            blk += 2 * 8192;
        }
        // epilogue: kb = KB-2 (X), KB-1 (Y)
        LOADG8(Y0, blk + 8192, 0);
        LOADG8(Y1, blk + 8192, 1);
        LOADA(a_nxt, KB - 1);
        MFMA8(a_cur, X0, 0);
        MFMA8(a_cur, X1, 1);
        a_cur = a_nxt;
        MFMA8(a_cur, Y0, 0);
        MFMA8(a_cur, Y1, 1);

        __syncthreads();  // all waves done reading h_lds

        // cell update, in-register (i,f,g,o co-located per lane); bias from LDS
#pragma unroll
        for (int s = 0; s < 4; ++s) {
            int j = wv * 64 + s * 16 + lr;
            float bi = bias_sh[0 * 256 + j];
            float bf = bias_sh[1 * 256 + j];
            float bgv = bias_sh[2 * 256 + j];
            float bo = bias_sh[3 * 256 + j];
#pragma unroll
            for (int r = 0; r < 4; ++r) {
                float iv = acc[0 * 4 + s][r] + bi;
                float fv = acc[1 * 4 + s][r] + bf;
                float gv = acc[2 * 4 + s][r] + bgv;
                float ov = acc[3 * 4 + s][r] + bo;
                float c = sigf(fv) * c_st[s][r] + sigf(iv) * tanhf_fast(gv);
                c_st[s][r] = c;
                float h = sigf(ov) * tanhf_fast(c);
                short hb = f2bf(h);
                int m = quad * 4 + r;
                h_lds[m][j] = hb;
                Hout[((size_t)t * BATCH + bbase + m) * 512 + dir * 256 + j] = hb;
            }
        }
        __syncthreads();  // new h visible before next step
    }
}

// ---------------- heads (fp32 output) --------------------------------------
__global__ __launch_bounds__(256) void lout_kernel(
    const short* __restrict__ h1, const float* __restrict__ Wlp,
    const float* __restrict__ blp, float* __restrict__ out)
{
    __shared__ float wl[6 * 512];
    for (int i = threadIdx.x; i < 6 * 512; i += 256) wl[i] = Wlp[i];
    __syncthreads();

    int idx = blockIdx.x * 256 + threadIdx.x;
    if (idx >= BATCH * 60) return;
    int b = idx & (BATCH - 1);
    int s = idx >> 10;
    const short* hrow = h1 + ((size_t)(s + 1) * BATCH + b) * 512;

    float acc[6];
#pragma unroll
    for (int j = 0; j < 6; ++j) acc[j] = blp[j];
    for (int k = 0; k < 512; k += 8) {
        short8 hv = *reinterpret_cast<const short8*>(hrow + k);
#pragma unroll
        for (int e = 0; e < 8; ++e) {
            float h = bf2f(hv[e]);
#pragma unroll
            for (int j = 0; j < 6; ++j) acc[j] += h * wl[j * 512 + k + e];
        }
    }
    float* orow = out + ((size_t)b * 60 + s) * 14;
#pragma unroll
    for (int j = 0; j < 6; ++j) orow[j] = acc[j];
}

__global__ __launch_bounds__(256) void gout_kernel(
    const short* __restrict__ h1, const float* __restrict__ Wgp,
    const float* __restrict__ bgp, float* __restrict__ out)
{
    __shared__ float wg[8 * 1024];
    for (int i = threadIdx.x; i < 8 * 1024; i += 256) wg[i] = Wgp[i];
    __syncthreads();

    int b = blockIdx.x * 256 + threadIdx.x;
    if (b >= BATCH) return;
    const short* ha = h1 + (size_t)b * 512;
    const short* hb = h1 + ((size_t)61 * BATCH + b) * 512;

    float acc[8];
#pragma unroll
    for (int j = 0; j < 8; ++j) acc[j] = bgp[j];
    for (int k = 0; k < 512; k += 8) {
        short8 h1v = *reinterpret_cast<const short8*>(ha + k);
        short8 h2v = *reinterpret_cast<const short8*>(hb + k);
#pragma unroll
        for (int e = 0; e < 8; ++e) {
            float v1 = bf2f(h1v[e]);
            float v2 = bf2f(h2v[e]);
#pragma unroll
            for (int j = 0; j < 8; ++j) {
                acc[j] += v1 * wg[j * 1024 + k + e];
                acc[j] += v2 * wg[j * 1024 + 512 + k + e];
            }
        }
    }
    for (int s = 0; s < 60; ++s) {
        float* orow = out + ((size_t)b * 60 + s) * 14 + 6;
#pragma unroll
        for (int j = 0; j < 8; ++j) orow[j] = acc[j];
    }
}

// ---------------- launch ---------------------------------------------------
extern "C" void kernel_launch(void* const* d_in, const int* in_sizes, int n_in,
                              void* d_out, int out_size, void* d_ws, size_t ws_size,
                              hipStream_t stream)
{
    const float* x    = (const float*)d_in[0];
    const float* Wg   = (const float*)d_in[1];
    const float* bg   = (const float*)d_in[2];
    const float* Wl   = (const float*)d_in[3];
    const float* bl   = (const float*)d_in[4];
    const float* Wih0 = (const float*)d_in[5];
    const float* Whh0 = (const float*)d_in[6];
    const float* bih0 = (const float*)d_in[7];
    const float* bhh0 = (const float*)d_in[8];
    const float* Wih1 = (const float*)d_in[9];
    const float* Whh1 = (const float*)d_in[10];
    const float* bih1 = (const float*)d_in[11];
    const float* bhh1 = (const float*)d_in[12];
    const float* Wgp  = (const float*)d_in[13];
    const float* bgp  = (const float*)d_in[14];
    const float* Wlp  = (const float*)d_in[15];
    const float* blp  = (const float*)d_in[16];
    float* out = (float*)d_out;

    const size_t seq_elems = (size_t)TSTEPS * BATCH * 256;   // 16,252,928
    const size_t h_elems   = (size_t)TSTEPS * BATCH * 512;   // 32,505,856
    const int    w0_elems  = 2 * 1024 * 512;                 // 1,048,576 (=8*16*8192)
    const int    w1_elems  = 2 * 1024 * 768;                 // 1,572,864 (=8*24*8192)

    short* seq = (short*)d_ws;
    short* h0  = seq + seq_elems;
    short* h1  = h0 + h_elems;
    short* wp0 = h1 + h_elems;
    short* wp1 = wp0 + w0_elems;
    const size_t need = (seq_elems + 2 * h_elems + w0_elems + w1_elems) * sizeof(short);
    if (ws_size < need) return;

    repack_kernel<<<(w0_elems + 255) / 256, 256, 0, stream>>>(Wih0, Whh0, wp0, 256);
    repack_kernel<<<(w1_elems + 255) / 256, 256, 0, stream>>>(Wih1, Whh1, wp1, 512);

    embed_kernel<<<BATCH, 256, 0, stream>>>(x, Wg, bg, Wl, bl, seq);
    lstm_kernel<512><<<128, 256, 0, stream>>>(seq, wp0, bih0, bhh0, h0);
    lstm_kernel<768><<<128, 256, 0, stream>>>(h0, wp1, bih1, bhh1, h1);
    lout_kernel<<<(BATCH * 60 + 255) / 256, 256, 0, stream>>>(h1, Wlp, blp, out);
    gout_kernel<<<(BATCH + 255) / 256, 256, 0, stream>>>(h1, Wgp, bgp, out);
}